// Round 19
// baseline (301.701 us; speedup 1.0000x reference)
//
#include <hip/hip_runtime.h>
#include <hip/hip_bf16.h>
#include <cstdint>
#include <cstddef>

// Problem constants
#define S_DIM 2048
#define H_DIM 2048
#define NHEAD 16
#define HD_DIM 128
#define O3    6144   // 3*H
#define BS    4096   // B*S
#define NBH   32     // B*NHEAD

typedef short  s16x4  __attribute__((ext_vector_type(4)));
typedef short  s16x8  __attribute__((ext_vector_type(8)));
typedef __bf16 bf16x8 __attribute__((ext_vector_type(8)));
typedef float  f32x4  __attribute__((ext_vector_type(4)));

__device__ __forceinline__ unsigned short f2bf(float f) {
  unsigned int b = __float_as_uint(f);
  b += 0x7FFFu + ((b >> 16) & 1u);          // round-to-nearest-even
  return (unsigned short)(b >> 16);
}
__device__ __forceinline__ float bf2f(unsigned short u) {
  return __uint_as_float(((unsigned int)u) << 16);
}
__device__ __forceinline__ bf16x8 load8(const unsigned short* p) {
  s16x8 r = *(const s16x8*)p;
  return __builtin_bit_cast(bf16x8, r);
}
__device__ __forceinline__ f32x4 mfma_bf16(bf16x8 a, bf16x8 b, f32x4 c) {
  return __builtin_amdgcn_mfma_f32_16x16x32_bf16(a, b, c, 0, 0, 0);
}
__device__ __forceinline__ void gload_lds16(const void* g, void* l) {
  __builtin_amdgcn_global_load_lds(
      (__attribute__((address_space(1))) unsigned int*)g,
      (__attribute__((address_space(3))) unsigned int*)l, 16, 0, 0);
}

// -------------------------------------------------- fused prep (one launch)
__global__ void prep_kernel(const float* __restrict__ hid,
                            const float* __restrict__ wqkv,
                            const float* __restrict__ wo,
                            unsigned short* __restrict__ hid_b,
                            unsigned short* __restrict__ wqkv_b,
                            unsigned short* __restrict__ wo_b,
                            float* __restrict__ cosT,
                            float* __restrict__ sinT) {
  const int nA = 2097152, nB = 3145728, nC = 1048576, nD = 131072;
  const int total = nA + nB + nC + nD;
  int stride = gridDim.x * blockDim.x;
  for (int i = blockIdx.x * blockDim.x + threadIdx.x; i < total; i += stride) {
    if (i < nA + nB + nC) {
      const float* src; unsigned short* dst; int j;
      if (i < nA)            { src = hid;  dst = hid_b;  j = i; }
      else if (i < nA + nB)  { src = wqkv; dst = wqkv_b; j = i - nA; }
      else                   { src = wo;   dst = wo_b;   j = i - nA - nB; }
      float4 v = ((const float4*)src)[j];
      ushort4 o;
      o.x = f2bf(v.x); o.y = f2bf(v.y); o.z = f2bf(v.z); o.w = f2bf(v.w);
      ((ushort4*)dst)[j] = o;
    } else {
      int idx = i - nA - nB - nC;          // 0..131071 = s*64 + d
      int s = idx >> 6, d = idx & 63;
      float inv = expf(-((float)d / 64.0f) * 9.210340371976184f);
      float ang = (float)s * inv;
      float sn, cs;
      sincosf(ang, &sn, &cs);
      cosT[idx] = cs;
      sinT[idx] = sn;
    }
  }
}

// ------------------------------------------- 256x256 GEMM (B^T), bf16 out
// C[M][N] = A[M][K] * Bw[N][K]^T. BM=BN=256, BK=64; 512 threads = 8 waves
// (2M x 4N), per-wave output 128x64 (acc[8][4]).
// Rationale (r11/r12/r18 model): at 128x256 the LDS read port (128 b128/tile
// ~1536cy) exceeds the MFMA floor (1242cy) -> 38% util ceiling. At 256^2,
// reads/MFMA = 0.375 (192 reads ~2304cy < MFMA 2483cy) -> MFMA-bound.
// Sync: 2 LDS buffers (128KB); tile t+1's staging issued at the TOP of tile
// t's compute (cover ~ full tile >> HBM latency, so the boundary vmcnt(0)
// is ~free); one barrier per tile; B-frags read once, reused across both
// M-halves; setprio around MFMA. XOR chunk swizzle both sides (G21).
__global__ __launch_bounds__(512, 1)
void gemm256_kernel(const unsigned short* __restrict__ A,
                    const unsigned short* __restrict__ Bw,
                    unsigned short* __restrict__ C, int M, int N, int K) {
  __shared__ __align__(16) unsigned short lA[2][256 * 64];   // 2 x 32KB
  __shared__ __align__(16) unsigned short lB[2][256 * 64];   // 2 x 32KB
  const int tid  = threadIdx.x;
  const int wave = tid >> 6, lane = tid & 63;
  const int wm = wave >> 2, wn = wave & 3;       // 2M x 4N wave grid
  const int lg = lane >> 4, ll = lane & 15;

  // chunked XCD swizzle (nwg = 384, % 8 == 0)
  const int nbx = gridDim.x;
  const int nwg = gridDim.x * gridDim.y;
  const int id  = blockIdx.y * nbx + blockIdx.x;
  const int swz = (id & 7) * (nwg >> 3) + (id >> 3);
  const int m0 = (swz / nbx) * 256, n0 = (swz % nbx) * 256;

  f32x4 acc[8][4];
#pragma unroll
  for (int i = 0; i < 8; ++i)
#pragma unroll
    for (int j = 0; j < 4; ++j) acc[i][j] = (f32x4){0.f, 0.f, 0.f, 0.f};

  // hoisted staging addresses; source chunk pre-swizzled with the read
  // involution cs = cb ^ ((cb>>3)&7)  (2048 chunks per operand, 4/thread)
  const unsigned short* aP[4];
  const unsigned short* bP[4];
  int aD[4], bD[4];
#pragma unroll
  for (int i = 0; i < 4; ++i) {
    int cb = i * 512 + tid;
    int cs = cb ^ ((cb >> 3) & 7);
    aP[i] = A + (size_t)(m0 + (cs >> 3)) * K + (cs & 7) * 8;
    bP[i] = Bw + (size_t)(n0 + (cs >> 3)) * K + (cs & 7) * 8;
    aD[i] = cb * 8;
    bD[i] = cb * 8;
  }

  auto STAGE = [&](int buf, int t) {
    const int kt = t << 6;
#pragma unroll
    for (int i = 0; i < 4; ++i) gload_lds16(aP[i] + kt, &lA[buf][aD[i]]);
#pragma unroll
    for (int i = 0; i < 4; ++i) gload_lds16(bP[i] + kt, &lB[buf][bD[i]]);
  };

  const int NT = K >> 6;   // 32
  STAGE(0, 0);
  asm volatile("s_waitcnt vmcnt(0)" ::: "memory");
  asm volatile("s_barrier" ::: "memory");

  for (int t = 0; t < NT; ++t) {
    const int cur = t & 1;
    // ---- issue next tile's staging FIRST: cover = this whole tile's compute
    if (t + 1 < NT) STAGE(cur ^ 1, t + 1);

    const char* lAc = (const char*)&lA[cur][0];
    const char* lBc = (const char*)&lB[cur][0];

    // ---- B fragments: read once, reused by both M-halves (8 ds_read_b128)
    bf16x8 bfr[4][2];
#pragma unroll
    for (int fr = 0; fr < 4; ++fr) {
      int r = wn * 64 + fr * 16 + ll;
#pragma unroll
      for (int kk = 0; kk < 2; ++kk) {
        int a = (r * 128 + kk * 64 + lg * 16) ^ ((r & 7) << 4);
        bfr[fr][kk] = load8((const unsigned short*)(lBc + a));
      }
    }

    // ---- 4 quadrant groups: {4 A-reads, 16 MFMA} each
#pragma unroll
    for (int mh = 0; mh < 2; ++mh)
#pragma unroll
      for (int kk = 0; kk < 2; ++kk) {
        bf16x8 af[4];
#pragma unroll
        for (int fq = 0; fq < 4; ++fq) {
          int r = wm * 128 + mh * 64 + fq * 16 + ll;
          int a = (r * 128 + kk * 64 + lg * 16) ^ ((r & 7) << 4);
          af[fq] = load8((const unsigned short*)(lAc + a));
        }
        __builtin_amdgcn_s_setprio(1);
#pragma unroll
        for (int fq = 0; fq < 4; ++fq)
#pragma unroll
          for (int fr = 0; fr < 4; ++fr)
            acc[mh * 4 + fq][fr] =
                mfma_bf16(af[fq], bfr[fr][kk], acc[mh * 4 + fq][fr]);
        __builtin_amdgcn_s_setprio(0);
      }

    // ---- boundary: staged loads were issued a full tile ago -> ~free wait
    if (t + 1 < NT) asm volatile("s_waitcnt vmcnt(0)" ::: "memory");
    asm volatile("s_barrier" ::: "memory");
  }

  // epilogue: C/D frag layout col = lane&15, row = (lane>>4)*4 + j
#pragma unroll
  for (int fm = 0; fm < 8; ++fm)
#pragma unroll
    for (int fn = 0; fn < 4; ++fn)
#pragma unroll
      for (int j = 0; j < 4; ++j) {
        int r   = m0 + wm * 128 + fm * 16 + lg * 4 + j;
        int col = n0 + wn * 64 + fn * 16 + ll;
        C[(size_t)r * N + col] = f2bf(acc[fm][fn][j]);
      }
}

// ------------------------------------------------- triple-buffered GEMM (B^T)
// Kept for the output projection (N=2048: 256 blocks = exactly 1 round; a
// 256^2 tile would idle half the CUs there). Best measured: 38% MfmaUtil.
template <bool OUT_BF16, bool QKV_MAP>
__global__ __launch_bounds__(512, 1)
void gemm3b_kernel(const unsigned short* __restrict__ A,
                   const unsigned short* __restrict__ Bw,
                   void* __restrict__ C, int M, int N, int K) {
  __shared__ __align__(16) unsigned short lA[3][128 * 64];   // 3 x 16KB
  __shared__ __align__(16) unsigned short lB[3][256 * 64];   // 3 x 32KB
  const int tid  = threadIdx.x;
  const int wave = tid >> 6, lane = tid & 63;
  const int wm = wave >> 2, wn = wave & 3;       // 2M x 4N wave grid
  const int lg = lane >> 4, ll = lane & 15;

  const int nbx = gridDim.x;
  const int id  = blockIdx.y * nbx + blockIdx.x;
  int m_tile, n_tile;
  if (QKV_MAP) {
    const int k = id & 7, q = id >> 3;
    const int ng = q >> 5, r = q & 31;
    m_tile = (k >> 1) * 8 + (r & 7);
    n_tile = (k & 1) * 12 + ng * 4 + (r >> 3);
  } else {
    const int nwg = gridDim.x * gridDim.y;
    const int swz = (id & 7) * (nwg >> 3) + (id >> 3);
    m_tile = swz / nbx;
    n_tile = swz % nbx;
  }
  const int m0 = m_tile * 128, n0 = n_tile * 256;

  f32x4 acc[4][4];
#pragma unroll
  for (int i = 0; i < 4; ++i)
#pragma unroll
    for (int j = 0; j < 4; ++j) acc[i][j] = (f32x4){0.f, 0.f, 0.f, 0.f};

  const unsigned short* aP[2];
  const unsigned short* bP[4];
  int aD[2], bD[4];
#pragma unroll
  for (int i = 0; i < 2; ++i) {
    int cb = (i * 8 + wave) * 64 + lane;
    int cs = cb ^ ((cb >> 3) & 7);
    aP[i] = A + (size_t)(m0 + (cs >> 3)) * K + (cs & 7) * 8;
    aD[i] = cb * 8;
  }
#pragma unroll
  for (int i = 0; i < 4; ++i) {
    int cb = (i * 8 + wave) * 64 + lane;
    int cs = cb ^ ((cb >> 3) & 7);
    bP[i] = Bw + (size_t)(n0 + (cs >> 3)) * K + (cs & 7) * 8;
    bD[i] = cb * 8;
  }

  auto STAGE = [&](int buf, int t) {
    const int kt = t << 6;
#pragma unroll
    for (int i = 0; i < 2; ++i) gload_lds16(aP[i] + kt, &lA[buf][aD[i]]);
#pragma unroll
    for (int i = 0; i < 4; ++i) gload_lds16(bP[i] + kt, &lB[buf][bD[i]]);
  };

  const int NT = K >> 6;
  STAGE(0, 0);
  if (NT > 1) {
    STAGE(1, 1);
    asm volatile("s_waitcnt vmcnt(6)" ::: "memory");
  } else {
    asm volatile("s_waitcnt vmcnt(0)" ::: "memory");
  }
  asm volatile("s_barrier" ::: "memory");

  for (int t = 0; t < NT; ++t) {
    const int cur = t % 3;
    const char* lAc = (const char*)&lA[cur][0];
    const char* lBc = (const char*)&lB[cur][0];

    bf16x8 af[4][2], bfr[2][2][2];
#pragma unroll
    for (int fq = 0; fq < 4; ++fq) {
      int r = wm * 64 + fq * 16 + ll;
#pragma unroll
      for (int kk = 0; kk < 2; ++kk) {
        int a = (r * 128 + kk * 64 + lg * 16) ^ ((r & 7) << 4);
        af[fq][kk] = load8((const unsigned short*)(lAc + a));
      }
    }
#pragma unroll
    for (int nh = 0; nh < 2; ++nh)
#pragma unroll
      for (int fq = 0; fq < 2; ++fq) {
        int r = wn * 64 + nh * 32 + fq * 16 + ll;
#pragma unroll
        for (int kk = 0; kk < 2; ++kk) {
          int a = (r * 128 + kk * 64 + lg * 16) ^ ((r & 7) << 4);
          bfr[nh][fq][kk] = load8((const unsigned short*)(lBc + a));
        }
      }

    if (t + 2 < NT) STAGE((t + 2) % 3, t + 2);

    __builtin_amdgcn_s_setprio(1);
#pragma unroll
    for (int nh = 0; nh < 2; ++nh)
#pragma unroll
      for (int fq = 0; fq < 4; ++fq)
#pragma unroll
        for (int gq = 0; gq < 2; ++gq)
#pragma unroll
          for (int kk = 0; kk < 2; ++kk)
            acc[fq][nh * 2 + gq] =
                mfma_bf16(af[fq][kk], bfr[nh][gq][kk], acc[fq][nh * 2 + gq]);
    __builtin_amdgcn_s_setprio(0);

    if (t + 2 < NT)
      asm volatile("s_waitcnt vmcnt(6)" ::: "memory");
    else if (t + 1 < NT)
      asm volatile("s_waitcnt vmcnt(0)" ::: "memory");
    asm volatile("s_barrier" ::: "memory");
  }

#pragma unroll
  for (int fm = 0; fm < 4; ++fm)
#pragma unroll
    for (int fn = 0; fn < 4; ++fn)
#pragma unroll
      for (int j = 0; j < 4; ++j) {
        int r   = m0 + wm * 64 + fm * 16 + lg * 4 + j;
        int col = n0 + wn * 64 + fn * 16 + ll;
        if (OUT_BF16)
          ((unsigned short*)C)[(size_t)r * N + col] = f2bf(acc[fm][fn][j]);
        else
          ((float*)C)[(size_t)r * N + col] = acc[fm][fn][j];
      }
}

// ---------------------------------------------------------------- RoPE q,k
__global__ void rope_qk_kernel(const unsigned short* __restrict__ mixed,
                               const float* __restrict__ cosT,
                               const float* __restrict__ sinT,
                               unsigned short* __restrict__ qr,
                               unsigned short* __restrict__ kr) {
  int m = blockIdx.x;              // 0..BS-1
  int s = m & (S_DIM - 1);
  int b = m >> 11;
  const unsigned short* row = mixed + (size_t)m * O3;
  int t = threadIdx.x;
  int h = t >> 4, dg = (t & 15) << 2;   // d = dg..dg+3
  int base = h * 384;
  s16x4 q0 = *(const s16x4*)(row + base + dg);
  s16x4 q1 = *(const s16x4*)(row + base + 64 + dg);
  s16x4 k0 = *(const s16x4*)(row + base + 128 + dg);
  s16x4 k1 = *(const s16x4*)(row + base + 192 + dg);
  float4 c4 = *(const float4*)(cosT + (s << 6) + dg);
  float4 s4 = *(const float4*)(sinT + (s << 6) + dg);
  size_t ob = ((size_t)(b * NHEAD + h) * S_DIM + s) * HD_DIM;
  s16x4 oq0, oq1, ok0, ok1;
  float cc[4] = {c4.x, c4.y, c4.z, c4.w};
  float ss[4] = {s4.x, s4.y, s4.z, s4.w};
#pragma unroll
  for (int i = 0; i < 4; ++i) {
    float q0f = bf2f((unsigned short)q0[i]), q1f = bf2f((unsigned short)q1[i]);
    float k0f = bf2f((unsigned short)k0[i]), k1f = bf2f((unsigned short)k1[i]);
    oq0[i] = (short)f2bf(q0f * cc[i] - q1f * ss[i]);
    oq1[i] = (short)f2bf(q1f * cc[i] + q0f * ss[i]);
    ok0[i] = (short)f2bf(k0f * cc[i] - k1f * ss[i]);
    ok1[i] = (short)f2bf(k1f * cc[i] + k0f * ss[i]);
  }
  *(s16x4*)(qr + ob + dg)      = oq0;
  *(s16x4*)(qr + ob + 64 + dg) = oq1;
  *(s16x4*)(kr + ob + dg)      = ok0;
  *(s16x4*)(kr + ob + 64 + dg) = ok1;
}

// ---------------------------------------------------------------- V transpose
__global__ __launch_bounds__(256)
void vtrans_kernel(const unsigned short* __restrict__ mixed,
                   unsigned short* __restrict__ vt) {
  __shared__ unsigned short t[64 * 65];
  int st = blockIdx.x, dt = blockIdx.y, bh = blockIdx.z;
  int b = bh >> 4, h = bh & 15;
  int s0 = st * 64, d0 = dt * 64;
  int tid = threadIdx.x;
#pragma unroll
  for (int it = 0; it < 2; ++it) {
    int c = it * 256 + tid;                 // 0..511
    int sl = c >> 3, dc = c & 7;
    const unsigned short* src =
        mixed + (size_t)(b * S_DIM + s0 + sl) * O3 + h * 384 + 256 + d0 + dc * 8;
    s16x8 v = *(const s16x8*)src;
#pragma unroll
    for (int i = 0; i < 8; ++i) t[(dc * 8 + i) * 65 + sl] = (unsigned short)v[i];
  }
  __syncthreads();
#pragma unroll
  for (int it = 0; it < 2; ++it) {
    int c = it * 256 + tid;
    int dl = c >> 3, sc = c & 7;
    s16x8 v;
#pragma unroll
    for (int i = 0; i < 8; ++i) v[i] = (short)t[dl * 65 + sc * 8 + i];
    *(s16x8*)(vt + ((size_t)bh * HD_DIM + d0 + dl) * S_DIM + s0 + sc * 8) = v;
  }
}

// ---------------------------------------------------------------- attention
// grid (p=16, bh=32), 256 threads = 4 waves, 16 q-rows each (seg = 64 rows).
// Balance: block p processes q-tiles {p, 31-p} -> 33 kv64-tiles every block.
__global__ __launch_bounds__(256, 2)
void attn_kernel(const unsigned short* __restrict__ qr,
                 const unsigned short* __restrict__ kr,
                 const unsigned short* __restrict__ vt,
                 unsigned short* __restrict__ out) {
  __shared__ __align__(16) unsigned short kbuf[2][64 * 128]; // 16KB/buf rows=s
  __shared__ __align__(16) unsigned short vbuf[2][128 * 64]; // 16KB/buf rows=d
  __shared__ __align__(16) unsigned short plds[4][16 * 72];  // per-wave P
  const int p = blockIdx.x, bh = blockIdx.y;
  const int wave = threadIdx.x >> 6, lane = threadIdx.x & 63;
  const int b = bh >> 4, h = bh & 15;
  const int lg = lane >> 4, ll = lane & 15;
  const unsigned short* Qb = qr + (size_t)bh * S_DIM * HD_DIM;
  const unsigned short* Kb = kr + (size_t)bh * S_DIM * HD_DIM;
  const unsigned short* Vb = vt + (size_t)bh * HD_DIM * S_DIM;
  const float kE  = 0.12752792f;   // (1/sqrt(128)) * log2(e)
  const float THR = 11.5416f;      // 8 * log2(e)  (T13 threshold, k-domain)
  unsigned short* pw = &plds[wave][0];

  for (int seg = 0; seg < 2; ++seg) {
    const int qt = seg ? (31 - p) : p;
    const int qbase = qt * 64 + wave * 16;
    const int ntb = qt + 1;                // causal kv64-tile count

    auto STAGE = [&](int buf, int t) {
      const int k0 = t * 64;
#pragma unroll
      for (int i = 0; i < 4; ++i) {
        int cb = (i * 4 + wave) * 64;      // wave-uniform
        int c  = cb + lane;                // K chunk 0..1023 (16/row)
        int cs = c ^ ((c >> 4) & 7);
        gload_lds16(Kb + (size_t)(k0 + (cs >> 4)) * HD_DIM + (cs & 15) * 8,
                    &kbuf[buf][cb * 8]);
      }
#pragma unroll
      for (int i = 0; i < 4; ++i) {
        int cb = (i * 4 + wave) * 64;
        int c  = cb + lane;                // V chunk 0..1023 (8/row)
        int cv = c ^ ((c >> 3) & 7);
        gload_lds16(Vb + (size_t)(cv >> 3) * S_DIM + k0 + (cv & 7) * 8,
                    &vbuf[buf][cb * 8]);
      }
    };

    bf16x8 aq[4];
#pragma unroll
    for (int kk = 0; kk < 4; ++kk)
      aq[kk] = load8(Qb + (size_t)(qbase + ll) * HD_DIM + kk * 32 + lg * 8);

    float mk[4], lsum[4];
    f32x4 o[8];
#pragma unroll
    for (int j = 0; j < 4; ++j) { mk[j] = -1e30f; lsum[j] = 0.f; }
#pragma unroll
    for (int f = 0; f < 8; ++f) o[f] = (f32x4){0.f, 0.f, 0.f, 0.f};

    STAGE(0, 0);
    __syncthreads();   // implicit vmcnt(0) drain

    for (int t = 0; t < ntb; ++t) {
      const int cur = t & 1;
      if (t + 1 < ntb) STAGE(cur ^ 1, t + 1);  // overlap with this tile's work
      const int k0 = t * 64;
      const bool diag = (t == ntb - 1);        // block-uniform

      // ---- QK^T: s[kf] covers kv rows k0+kf*16..+16, K from swizzled LDS
      f32x4 s[4];
#pragma unroll
      for (int kf = 0; kf < 4; ++kf) s[kf] = (f32x4){0.f, 0.f, 0.f, 0.f};
      const char* kb = (const char*)&kbuf[cur][0];
      __builtin_amdgcn_s_setprio(1);
#pragma unroll
      for (int kf = 0; kf < 4; ++kf) {
        int r = kf * 16 + ll;
#pragma unroll
        for (int kk = 0; kk < 4; ++kk) {
          int a = (r * 256 + kk * 64 + lg * 16) ^ ((r & 7) << 4);
          s[kf] = mfma_bf16(aq[kk], load8((const unsigned short*)(kb + a)), s[kf]);
        }
      }
      __builtin_amdgcn_s_setprio(0);

      // ---- causal mask (diagonal tile only; raw-score domain)
      if (diag) {
#pragma unroll
        for (int kf = 0; kf < 4; ++kf) {
          int kcol = k0 + kf * 16 + ll;
#pragma unroll
          for (int j = 0; j < 4; ++j) {
            int qrow = qbase + lg * 4 + j;
            if (kcol > qrow) s[kf][j] = -1e31f;
          }
        }
      }

      // ---- defer-max online softmax (T13). mk is running max * kE.
      float pmax[4];
      bool ok = true;
#pragma unroll
      for (int j = 0; j < 4; ++j) {
        pmax[j] = fmaxf(fmaxf(s[0][j], s[1][j]), fmaxf(s[2][j], s[3][j]));
        ok = ok && (pmax[j] * kE - mk[j] <= THR);
      }
      if (!__all(ok)) {                      // rare: ~once per segment
#pragma unroll
        for (int j = 0; j < 4; ++j) {
          float rm = pmax[j] * kE;
#pragma unroll
          for (int off = 1; off < 16; off <<= 1)
            rm = fmaxf(rm, __shfl_xor(rm, off, 64));
          rm = fmaxf(rm, mk[j]);
          float corr = exp2f(mk[j] - rm);
          mk[j] = rm;
          lsum[j] *= corr;
#pragma unroll
          for (int f = 0; f < 8; ++f) o[f][j] *= corr;
        }
      }
      // P = exp2(s*kE - mk)  (bounded by 2^THR = e^8); per-lane l partials.
#pragma unroll
      for (int j = 0; j < 4; ++j) {
        int prow = (lg * 4 + j) * 72;
#pragma unroll
        for (int kf = 0; kf < 4; ++kf) {
          float e = exp2f(fmaf(s[kf][j], kE, -mk[j]));
          lsum[j] += e;
          pw[prow + kf * 16 + ll] = f2bf(e);
        }
      }

      // ---- PV from swizzled V LDS (P round-trip through per-wave LDS)
      bf16x8 pa0 = load8(&pw[ll * 72 + lg * 8]);
      bf16x8 pa1 = load8(&pw[ll * 72 + 32 + lg * 8]);
      const char* vb = (const char*)&vbuf[cur][0];
      __builtin_amdgcn_s_setprio(1);
#pragma unroll
      for (int f = 0; f < 8; ++f) {
        int rv = f * 16 + ll;
        int a0 = (rv * 128 + lg * 16) ^ ((rv & 7) << 4);
        int a1 = (rv * 128 + 64 + lg * 16) ^ ((rv & 7) << 4);
        o[f] = mfma_bf16(pa0, load8((const unsigned short*)(vb + a0)), o[f]);
        o[f] = mfma_bf16(pa1, load8((const unsigned short*)(vb + a1)), o[f]);
      }
      __builtin_amdgcn_s_setprio(0);

      __syncthreads();   // drains vmcnt (next tile staged) + protects buffers
    }

    // ---- epilogue: reduce l partials once, normalize, store
#pragma unroll
    for (int j = 0; j < 4; ++j) {
      float l = lsum[j];
#pragma unroll
      for (int off = 1; off < 16; off <<= 1) l += __shfl_xor(l, off, 64);
      lsum[j] = 1.0f / l;
    }
#pragma unroll
    for (int f = 0; f < 8; ++f)
#pragma unroll
      for (int j = 0; j < 4; ++j) {
        int srow = qbase + lg * 4 + j;
        out[((size_t)(b * S_DIM + srow)) * H_DIM + h * HD_DIM + f * 16 + ll] =
            f2bf(o[f][j] * lsum[j]);
      }
  }
}

// ---------------------------------------------------------------- launch
extern "C" void kernel_launch(void* const* d_in, const int* in_sizes, int n_in,
                              void* d_out, int out_size, void* d_ws, size_t ws_size,
                              hipStream_t stream) {
  (void)in_sizes; (void)n_in; (void)out_size; (void)ws_size;
  const float* hidden = (const float*)d_in[0];
  const float* wqkv   = (const float*)d_in[1];
  const float* wo     = (const float*)d_in[2];
  char* ws = (char*)d_ws;
  unsigned short* hid_b  = (unsigned short*)(ws);               // 16,777,216
  unsigned short* wqkv_b = (unsigned short*)(ws + 16777216);    // 25,165,824
  unsigned short* wo_b   = (unsigned short*)(ws + 41943040);    //  8,388,608
  unsigned short* mixed  = (unsigned short*)(ws + 50331648);    // 50,331,648
  unsigned short* q_r    = (unsigned short*)(ws + 100663296);   // 16,777,216
  unsigned short* k_r    = (unsigned short*)(ws + 117440512);   // 16,777,216
  unsigned short* v_t    = (unsigned short*)(ws + 134217728);   // 16,777,216
  unsigned short* attn   = (unsigned short*)(ws + 150994944);   // 16,777,216
  float* cosT            = (float*)(ws + 167772160);            //    524,288
  float* sinT            = (float*)(ws + 168296448);            //    524,288

  prep_kernel<<<2048, 256, 0, stream>>>(hidden, wqkv, wo, hid_b, wqkv_b, wo_b,
                                        cosT, sinT);

  // QKV projection: 256^2 tile, grid 24x16 = 384 blocks (1.5 rounds)
  gemm256_kernel<<<dim3(O3 / 256, BS / 256), 512, 0, stream>>>(
      hid_b, wqkv_b, mixed, BS, O3, H_DIM);

  rope_qk_kernel<<<BS, 256, 0, stream>>>(mixed, cosT, sinT, q_r, k_r);
  vtrans_kernel<<<dim3(32, 2, 32), 256, 0, stream>>>(mixed, v_t);

  attn_kernel<<<dim3(16, 32), 256, 0, stream>>>(q_r, k_r, v_t, attn);

  // output projection: grid 8x32 = 256 = exactly 1 round; chunked map
  gemm3b_kernel<false, false><<<dim3(H_DIM / 256, BS / 128), 512, 0, stream>>>(
      attn, wo_b, d_out, BS, H_DIM, H_DIM);
}

// Round 20
// 264.194 us; speedup vs baseline: 1.1420x; 1.1420x over previous
//
#include <hip/hip_runtime.h>
#include <hip/hip_bf16.h>
#include <cstdint>
#include <cstddef>

// Problem constants
#define S_DIM 2048
#define H_DIM 2048
#define NHEAD 16
#define HD_DIM 128
#define O3    6144   // 3*H
#define BS    4096   // B*S
#define NBH   32     // B*NHEAD

typedef short  s16x4  __attribute__((ext_vector_type(4)));
typedef short  s16x8  __attribute__((ext_vector_type(8)));
typedef __bf16 bf16x8 __attribute__((ext_vector_type(8)));
typedef float  f32x4  __attribute__((ext_vector_type(4)));

__device__ __forceinline__ unsigned short f2bf(float f) {
  unsigned int b = __float_as_uint(f);
  b += 0x7FFFu + ((b >> 16) & 1u);          // round-to-nearest-even
  return (unsigned short)(b >> 16);
}
__device__ __forceinline__ float bf2f(unsigned short u) {
  return __uint_as_float(((unsigned int)u) << 16);
}
__device__ __forceinline__ bf16x8 load8(const unsigned short* p) {
  s16x8 r = *(const s16x8*)p;
  return __builtin_bit_cast(bf16x8, r);
}
__device__ __forceinline__ f32x4 mfma_bf16(bf16x8 a, bf16x8 b, f32x4 c) {
  return __builtin_amdgcn_mfma_f32_16x16x32_bf16(a, b, c, 0, 0, 0);
}
__device__ __forceinline__ void gload_lds16(const void* g, void* l) {
  __builtin_amdgcn_global_load_lds(
      (__attribute__((address_space(1))) unsigned int*)g,
      (__attribute__((address_space(3))) unsigned int*)l, 16, 0, 0);
}

// -------------------------------------------------- fused prep (one launch)
__global__ void prep_kernel(const float* __restrict__ hid,
                            const float* __restrict__ wqkv,
                            const float* __restrict__ wo,
                            unsigned short* __restrict__ hid_b,
                            unsigned short* __restrict__ wqkv_b,
                            unsigned short* __restrict__ wo_b,
                            float* __restrict__ cosT,
                            float* __restrict__ sinT) {
  const int nA = 2097152, nB = 3145728, nC = 1048576, nD = 131072;
  const int total = nA + nB + nC + nD;
  int stride = gridDim.x * blockDim.x;
  for (int i = blockIdx.x * blockDim.x + threadIdx.x; i < total; i += stride) {
    if (i < nA + nB + nC) {
      const float* src; unsigned short* dst; int j;
      if (i < nA)            { src = hid;  dst = hid_b;  j = i; }
      else if (i < nA + nB)  { src = wqkv; dst = wqkv_b; j = i - nA; }
      else                   { src = wo;   dst = wo_b;   j = i - nA - nB; }
      float4 v = ((const float4*)src)[j];
      ushort4 o;
      o.x = f2bf(v.x); o.y = f2bf(v.y); o.z = f2bf(v.z); o.w = f2bf(v.w);
      ((ushort4*)dst)[j] = o;
    } else {
      int idx = i - nA - nB - nC;          // 0..131071 = s*64 + d
      int s = idx >> 6, d = idx & 63;
      float inv = expf(-((float)d / 64.0f) * 9.210340371976184f);
      float ang = (float)s * inv;
      float sn, cs;
      sincosf(ang, &sn, &cs);
      cosT[idx] = cs;
      sinT[idx] = sn;
    }
  }
}

// ------------------------------------------------- triple-buffered GEMM (B^T)
// PROVEN BEST (r10/r11/r18: QKV 115.7-116.3us, MfmaUtil ~38%, 0 conflicts).
// BM=128, BN=256, BK=64; 512 threads = 8 waves (2M x 4N), 64x64 C per wave.
// 3 LDS buffers: compute tile t from buf[t%3], tile t+1 landed, t+2 staging
// -> boundary wait vmcnt(6), never drain-0 in the loop (T4).
// Ledger of tried-and-rejected alternates: 4-phase drain0 = 151us; A-in-reg =
// 255us (uncoalesced); 256^2 2buf drain0 = 145us (no stall absorber + tail).
template <bool OUT_BF16, bool QKV_MAP>
__global__ __launch_bounds__(512, 1)
void gemm3b_kernel(const unsigned short* __restrict__ A,
                   const unsigned short* __restrict__ Bw,
                   void* __restrict__ C, int M, int N, int K) {
  __shared__ __align__(16) unsigned short lA[3][128 * 64];   // 3 x 16KB
  __shared__ __align__(16) unsigned short lB[3][256 * 64];   // 3 x 32KB
  const int tid  = threadIdx.x;
  const int wave = tid >> 6, lane = tid & 63;
  const int wm = wave >> 2, wn = wave & 3;       // 2M x 4N wave grid
  const int lg = lane >> 4, ll = lane & 15;

  const int nbx = gridDim.x;
  const int id  = blockIdx.y * nbx + blockIdx.x;
  int m_tile, n_tile;
  if (QKV_MAP) {
    // grid 24(n) x 32(m): XCD k=id&7 -> (mband,nband)=(k>>1,k&1);
    // within: windows of 8m x 4n. Bijective. (r11: FETCH 307->98 MB)
    const int k = id & 7, q = id >> 3;
    const int ng = q >> 5, r = q & 31;
    m_tile = (k >> 1) * 8 + (r & 7);
    n_tile = (k & 1) * 12 + ng * 4 + (r >> 3);
  } else {
    // chunked XCD swizzle (nwg % 8 == 0)
    const int nwg = gridDim.x * gridDim.y;
    const int swz = (id & 7) * (nwg >> 3) + (id >> 3);
    m_tile = swz / nbx;
    n_tile = swz % nbx;
  }
  const int m0 = m_tile * 128, n0 = n_tile * 256;

  f32x4 acc[4][4];
#pragma unroll
  for (int i = 0; i < 4; ++i)
#pragma unroll
    for (int j = 0; j < 4; ++j) acc[i][j] = (f32x4){0.f, 0.f, 0.f, 0.f};

  // hoisted staging addresses; source pre-swizzled with the read involution
  // cs = cb ^ ((cb>>3)&7) (G21).
  const unsigned short* aP[2];
  const unsigned short* bP[4];
  int aD[2], bD[4];
#pragma unroll
  for (int i = 0; i < 2; ++i) {
    int cb = (i * 8 + wave) * 64 + lane;
    int cs = cb ^ ((cb >> 3) & 7);
    aP[i] = A + (size_t)(m0 + (cs >> 3)) * K + (cs & 7) * 8;
    aD[i] = cb * 8;
  }
#pragma unroll
  for (int i = 0; i < 4; ++i) {
    int cb = (i * 8 + wave) * 64 + lane;
    int cs = cb ^ ((cb >> 3) & 7);
    bP[i] = Bw + (size_t)(n0 + (cs >> 3)) * K + (cs & 7) * 8;
    bD[i] = cb * 8;
  }

  auto STAGE = [&](int buf, int t) {
    const int kt = t << 6;
#pragma unroll
    for (int i = 0; i < 2; ++i) gload_lds16(aP[i] + kt, &lA[buf][aD[i]]);
#pragma unroll
    for (int i = 0; i < 4; ++i) gload_lds16(bP[i] + kt, &lB[buf][bD[i]]);
  };

  const int NT = K >> 6;
  STAGE(0, 0);
  if (NT > 1) {
    STAGE(1, 1);
    asm volatile("s_waitcnt vmcnt(6)" ::: "memory");
  } else {
    asm volatile("s_waitcnt vmcnt(0)" ::: "memory");
  }
  asm volatile("s_barrier" ::: "memory");

  for (int t = 0; t < NT; ++t) {
    const int cur = t % 3;
    const char* lAc = (const char*)&lA[cur][0];
    const char* lBc = (const char*)&lB[cur][0];

    bf16x8 af[4][2], bfr[2][2][2];
#pragma unroll
    for (int fq = 0; fq < 4; ++fq) {
      int r = wm * 64 + fq * 16 + ll;
#pragma unroll
      for (int kk = 0; kk < 2; ++kk) {
        int a = (r * 128 + kk * 64 + lg * 16) ^ ((r & 7) << 4);
        af[fq][kk] = load8((const unsigned short*)(lAc + a));
      }
    }
#pragma unroll
    for (int nh = 0; nh < 2; ++nh)
#pragma unroll
      for (int fq = 0; fq < 2; ++fq) {
        int r = wn * 64 + nh * 32 + fq * 16 + ll;
#pragma unroll
        for (int kk = 0; kk < 2; ++kk) {
          int a = (r * 128 + kk * 64 + lg * 16) ^ ((r & 7) << 4);
          bfr[nh][fq][kk] = load8((const unsigned short*)(lBc + a));
        }
      }

    if (t + 2 < NT) STAGE((t + 2) % 3, t + 2);

    __builtin_amdgcn_s_setprio(1);
#pragma unroll
    for (int nh = 0; nh < 2; ++nh)
#pragma unroll
      for (int fq = 0; fq < 4; ++fq)
#pragma unroll
        for (int gq = 0; gq < 2; ++gq)
#pragma unroll
          for (int kk = 0; kk < 2; ++kk)
            acc[fq][nh * 2 + gq] =
                mfma_bf16(af[fq][kk], bfr[nh][gq][kk], acc[fq][nh * 2 + gq]);
    __builtin_amdgcn_s_setprio(0);

    if (t + 2 < NT)
      asm volatile("s_waitcnt vmcnt(6)" ::: "memory");
    else if (t + 1 < NT)
      asm volatile("s_waitcnt vmcnt(0)" ::: "memory");
    asm volatile("s_barrier" ::: "memory");
  }

  // epilogue: C/D frag layout col = lane&15, row = (lane>>4)*4 + j
#pragma unroll
  for (int fm = 0; fm < 4; ++fm)
#pragma unroll
    for (int fn = 0; fn < 4; ++fn)
#pragma unroll
      for (int j = 0; j < 4; ++j) {
        int r   = m0 + wm * 64 + fm * 16 + lg * 4 + j;
        int col = n0 + wn * 64 + fn * 16 + ll;
        if (OUT_BF16)
          ((unsigned short*)C)[(size_t)r * N + col] = f2bf(acc[fm][fn][j]);
        else
          ((float*)C)[(size_t)r * N + col] = acc[fm][fn][j];
      }
}

// ---------------------------------------------------------------- RoPE q,k
__global__ void rope_qk_kernel(const unsigned short* __restrict__ mixed,
                               const float* __restrict__ cosT,
                               const float* __restrict__ sinT,
                               unsigned short* __restrict__ qr,
                               unsigned short* __restrict__ kr) {
  int m = blockIdx.x;              // 0..BS-1
  int s = m & (S_DIM - 1);
  int b = m >> 11;
  const unsigned short* row = mixed + (size_t)m * O3;
  int t = threadIdx.x;
  int h = t >> 4, dg = (t & 15) << 2;   // d = dg..dg+3
  int base = h * 384;
  s16x4 q0 = *(const s16x4*)(row + base + dg);
  s16x4 q1 = *(const s16x4*)(row + base + 64 + dg);
  s16x4 k0 = *(const s16x4*)(row + base + 128 + dg);
  s16x4 k1 = *(const s16x4*)(row + base + 192 + dg);
  float4 c4 = *(const float4*)(cosT + (s << 6) + dg);
  float4 s4 = *(const float4*)(sinT + (s << 6) + dg);
  size_t ob = ((size_t)(b * NHEAD + h) * S_DIM + s) * HD_DIM;
  s16x4 oq0, oq1, ok0, ok1;
  float cc[4] = {c4.x, c4.y, c4.z, c4.w};
  float ss[4] = {s4.x, s4.y, s4.z, s4.w};
#pragma unroll
  for (int i = 0; i < 4; ++i) {
    float q0f = bf2f((unsigned short)q0[i]), q1f = bf2f((unsigned short)q1[i]);
    float k0f = bf2f((unsigned short)k0[i]), k1f = bf2f((unsigned short)k1[i]);
    oq0[i] = (short)f2bf(q0f * cc[i] - q1f * ss[i]);
    oq1[i] = (short)f2bf(q1f * cc[i] + q0f * ss[i]);
    ok0[i] = (short)f2bf(k0f * cc[i] - k1f * ss[i]);
    ok1[i] = (short)f2bf(k1f * cc[i] + k0f * ss[i]);
  }
  *(s16x4*)(qr + ob + dg)      = oq0;
  *(s16x4*)(qr + ob + 64 + dg) = oq1;
  *(s16x4*)(kr + ob + dg)      = ok0;
  *(s16x4*)(kr + ob + 64 + dg) = ok1;
}

// ---------------------------------------------------------------- V transpose
__global__ __launch_bounds__(256)
void vtrans_kernel(const unsigned short* __restrict__ mixed,
                   unsigned short* __restrict__ vt) {
  __shared__ unsigned short t[64 * 65];
  int st = blockIdx.x, dt = blockIdx.y, bh = blockIdx.z;
  int b = bh >> 4, h = bh & 15;
  int s0 = st * 64, d0 = dt * 64;
  int tid = threadIdx.x;
#pragma unroll
  for (int it = 0; it < 2; ++it) {
    int c = it * 256 + tid;                 // 0..511
    int sl = c >> 3, dc = c & 7;
    const unsigned short* src =
        mixed + (size_t)(b * S_DIM + s0 + sl) * O3 + h * 384 + 256 + d0 + dc * 8;
    s16x8 v = *(const s16x8*)src;
#pragma unroll
    for (int i = 0; i < 8; ++i) t[(dc * 8 + i) * 65 + sl] = (unsigned short)v[i];
  }
  __syncthreads();
#pragma unroll
  for (int it = 0; it < 2; ++it) {
    int c = it * 256 + tid;
    int dl = c >> 3, sc = c & 7;
    s16x8 v;
#pragma unroll
    for (int i = 0; i < 8; ++i) v[i] = (short)t[dl * 65 + sc * 8 + i];
    *(s16x8*)(vt + ((size_t)bh * HD_DIM + d0 + dl) * S_DIM + s0 + sc * 8) = v;
  }
}

// ---------------------------------------------------------------- attention
// 8-WAVE variant: grid (p=8, bh=32) = 256 blocks, 512 threads = 8 waves,
// 16 q-rows each -> block = 128 q-rows. Pairing: block p does q-tiles
// {p, 15-p}: ntb = 2qt+2 -> (2p+2)+(2(15-p)+2) = 36 kv64-tiles EVERY block.
// vs r18 (4-wave/64-row, 2 blocks/CU): same 8 waves/CU and ~same MFMA, but
// staged bytes and barrier count per CU HALVED (36 vs 66 tile-stages).
// Mask window: last TWO tiles (waves 0-3's diagonal is at t=ntb-2; their
// t=ntb-1 tile is fully masked -> contributes 0 exactly).
__global__ __launch_bounds__(512, 1)
void attn_kernel(const unsigned short* __restrict__ qr,
                 const unsigned short* __restrict__ kr,
                 const unsigned short* __restrict__ vt,
                 unsigned short* __restrict__ out) {
  __shared__ __align__(16) unsigned short kbuf[2][64 * 128]; // 16KB/buf rows=s
  __shared__ __align__(16) unsigned short vbuf[2][128 * 64]; // 16KB/buf rows=d
  __shared__ __align__(16) unsigned short plds[8][16 * 72];  // per-wave P
  const int p = blockIdx.x, bh = blockIdx.y;
  const int wave = threadIdx.x >> 6, lane = threadIdx.x & 63;
  const int b = bh >> 4, h = bh & 15;
  const int lg = lane >> 4, ll = lane & 15;
  const unsigned short* Qb = qr + (size_t)bh * S_DIM * HD_DIM;
  const unsigned short* Kb = kr + (size_t)bh * S_DIM * HD_DIM;
  const unsigned short* Vb = vt + (size_t)bh * HD_DIM * S_DIM;
  const float kE  = 0.12752792f;   // (1/sqrt(128)) * log2(e)
  const float THR = 11.5416f;      // 8 * log2(e)  (T13 threshold, k-domain)
  unsigned short* pw = &plds[wave][0];

  for (int seg = 0; seg < 2; ++seg) {
    const int qt = seg ? (15 - p) : p;         // 128-row q-tile index
    const int qbase = qt * 128 + wave * 16;
    const int ntb = 2 * qt + 2;                // causal kv64-tile count

    auto STAGE = [&](int buf, int t) {
      const int k0 = t * 64;
#pragma unroll
      for (int i = 0; i < 2; ++i) {
        int cb = (i * 8 + wave) * 64;      // wave-uniform
        int c  = cb + lane;                // K chunk 0..1023 (16/row)
        int cs = c ^ ((c >> 4) & 7);
        gload_lds16(Kb + (size_t)(k0 + (cs >> 4)) * HD_DIM + (cs & 15) * 8,
                    &kbuf[buf][cb * 8]);
      }
#pragma unroll
      for (int i = 0; i < 2; ++i) {
        int cb = (i * 8 + wave) * 64;
        int c  = cb + lane;                // V chunk 0..1023 (8/row)
        int cv = c ^ ((c >> 3) & 7);
        gload_lds16(Vb + (size_t)(cv >> 3) * S_DIM + k0 + (cv & 7) * 8,
                    &vbuf[buf][cb * 8]);
      }
    };

    bf16x8 aq[4];
#pragma unroll
    for (int kk = 0; kk < 4; ++kk)
      aq[kk] = load8(Qb + (size_t)(qbase + ll) * HD_DIM + kk * 32 + lg * 8);

    float mk[4], lsum[4];
    f32x4 o[8];
#pragma unroll
    for (int j = 0; j < 4; ++j) { mk[j] = -1e30f; lsum[j] = 0.f; }
#pragma unroll
    for (int f = 0; f < 8; ++f) o[f] = (f32x4){0.f, 0.f, 0.f, 0.f};

    STAGE(0, 0);
    __syncthreads();   // implicit vmcnt(0) drain

    for (int t = 0; t < ntb; ++t) {
      const int cur = t & 1;
      if (t + 1 < ntb) STAGE(cur ^ 1, t + 1);  // overlap with this tile's work
      const int k0 = t * 64;
      const bool maskt = (t >= ntb - 2);       // block-uniform mask window

      // ---- QK^T: s[kf] covers kv rows k0+kf*16..+16, K from swizzled LDS
      f32x4 s[4];
#pragma unroll
      for (int kf = 0; kf < 4; ++kf) s[kf] = (f32x4){0.f, 0.f, 0.f, 0.f};
      const char* kb = (const char*)&kbuf[cur][0];
      __builtin_amdgcn_s_setprio(1);
#pragma unroll
      for (int kf = 0; kf < 4; ++kf) {
        int r = kf * 16 + ll;
#pragma unroll
        for (int kk = 0; kk < 4; ++kk) {
          int a = (r * 256 + kk * 64 + lg * 16) ^ ((r & 7) << 4);
          s[kf] = mfma_bf16(aq[kk], load8((const unsigned short*)(kb + a)), s[kf]);
        }
      }
      __builtin_amdgcn_s_setprio(0);

      // ---- causal mask (last two tiles only; raw-score domain)
      if (maskt) {
#pragma unroll
        for (int kf = 0; kf < 4; ++kf) {
          int kcol = k0 + kf * 16 + ll;
#pragma unroll
          for (int j = 0; j < 4; ++j) {
            int qrow = qbase + lg * 4 + j;
            if (kcol > qrow) s[kf][j] = -1e31f;
          }
        }
      }

      // ---- defer-max online softmax (T13). mk is running max * kE.
      float pmax[4];
      bool ok = true;
#pragma unroll
      for (int j = 0; j < 4; ++j) {
        pmax[j] = fmaxf(fmaxf(s[0][j], s[1][j]), fmaxf(s[2][j], s[3][j]));
        ok = ok && (pmax[j] * kE - mk[j] <= THR);
      }
      if (!__all(ok)) {                      // rare: ~once per segment
#pragma unroll
        for (int j = 0; j < 4; ++j) {
          float rm = pmax[j] * kE;
#pragma unroll
          for (int off = 1; off < 16; off <<= 1)
            rm = fmaxf(rm, __shfl_xor(rm, off, 64));
          rm = fmaxf(rm, mk[j]);
          float corr = exp2f(mk[j] - rm);
          mk[j] = rm;
          lsum[j] *= corr;
#pragma unroll
          for (int f = 0; f < 8; ++f) o[f][j] *= corr;
        }
      }
      // P = exp2(s*kE - mk)  (bounded by 2^THR = e^8); per-lane l partials.
#pragma unroll
      for (int j = 0; j < 4; ++j) {
        int prow = (lg * 4 + j) * 72;
#pragma unroll
        for (int kf = 0; kf < 4; ++kf) {
          float e = exp2f(fmaf(s[kf][j], kE, -mk[j]));
          lsum[j] += e;
          pw[prow + kf * 16 + ll] = f2bf(e);
        }
      }

      // ---- PV from swizzled V LDS (P round-trip through per-wave LDS)
      bf16x8 pa0 = load8(&pw[ll * 72 + lg * 8]);
      bf16x8 pa1 = load8(&pw[ll * 72 + 32 + lg * 8]);
      const char* vb = (const char*)&vbuf[cur][0];
      __builtin_amdgcn_s_setprio(1);
#pragma unroll
      for (int f = 0; f < 8; ++f) {
        int rv = f * 16 + ll;
        int a0 = (rv * 128 + lg * 16) ^ ((rv & 7) << 4);
        int a1 = (rv * 128 + 64 + lg * 16) ^ ((rv & 7) << 4);
        o[f] = mfma_bf16(pa0, load8((const unsigned short*)(vb + a0)), o[f]);
        o[f] = mfma_bf16(pa1, load8((const unsigned short*)(vb + a1)), o[f]);
      }
      __builtin_amdgcn_s_setprio(0);

      __syncthreads();   // drains vmcnt (next tile staged) + protects buffers
    }

    // ---- epilogue: reduce l partials once, normalize, store
#pragma unroll
    for (int j = 0; j < 4; ++j) {
      float l = lsum[j];
#pragma unroll
      for (int off = 1; off < 16; off <<= 1) l += __shfl_xor(l, off, 64);
      lsum[j] = 1.0f / l;
    }
#pragma unroll
    for (int f = 0; f < 8; ++f)
#pragma unroll
      for (int j = 0; j < 4; ++j) {
        int srow = qbase + lg * 4 + j;
        out[((size_t)(b * S_DIM + srow)) * H_DIM + h * HD_DIM + f * 16 + ll] =
            f2bf(o[f][j] * lsum[j]);
      }
  }
}

// ---------------------------------------------------------------- launch
extern "C" void kernel_launch(void* const* d_in, const int* in_sizes, int n_in,
                              void* d_out, int out_size, void* d_ws, size_t ws_size,
                              hipStream_t stream) {
  (void)in_sizes; (void)n_in; (void)out_size; (void)ws_size;
  const float* hidden = (const float*)d_in[0];
  const float* wqkv   = (const float*)d_in[1];
  const float* wo     = (const float*)d_in[2];
  char* ws = (char*)d_ws;
  unsigned short* hid_b  = (unsigned short*)(ws);               // 16,777,216
  unsigned short* wqkv_b = (unsigned short*)(ws + 16777216);    // 25,165,824
  unsigned short* wo_b   = (unsigned short*)(ws + 41943040);    //  8,388,608
  unsigned short* mixed  = (unsigned short*)(ws + 50331648);    // 50,331,648
  unsigned short* q_r    = (unsigned short*)(ws + 100663296);   // 16,777,216
  unsigned short* k_r    = (unsigned short*)(ws + 117440512);   // 16,777,216
  unsigned short* v_t    = (unsigned short*)(ws + 134217728);   // 16,777,216
  unsigned short* attn   = (unsigned short*)(ws + 150994944);   // 16,777,216
  float* cosT            = (float*)(ws + 167772160);            //    524,288
  float* sinT            = (float*)(ws + 168296448);            //    524,288

  prep_kernel<<<2048, 256, 0, stream>>>(hidden, wqkv, wo, hid_b, wqkv_b, wo_b,
                                        cosT, sinT);

  // QKV projection: grid 24x32 = 768 = exactly 3 rounds; L2-aware XCD map
  gemm3b_kernel<true, true><<<dim3(O3 / 256, BS / 128), 512, 0, stream>>>(
      hid_b, wqkv_b, mixed, BS, O3, H_DIM);

  rope_qk_kernel<<<BS, 256, 0, stream>>>(mixed, cosT, sinT, q_r, k_r);
  vtrans_kernel<<<dim3(32, 2, 32), 256, 0, stream>>>(mixed, v_t);

  // attention: 8-wave blocks, grid 8x32 = 256 blocks = exactly 1/CU
  attn_kernel<<<dim3(8, 32), 512, 0, stream>>>(q_r, k_r, v_t, attn);

  // output projection: grid 8x32 = 256 = exactly 1 round; chunked map
  gemm3b_kernel<false, false><<<dim3(H_DIM / 256, BS / 128), 512, 0, stream>>>(
      attn, wo_b, d_out, BS, H_DIM, H_DIM);
}